// Round 3
// baseline (212.777 us; speedup 1.0000x reference)
//
#include <hip/hip_runtime.h>

// out[b,c,i,j] = x[b,c,i,j] * (i%3!=0) * (j%3!=0)
// Unfold->fold composite == elementwise separable 0/1 mask (see prior rounds).
//
// R2 change: 8 float4s per thread, stride 256 f4 (4 KB) between accesses,
// block covers a contiguous 32 KB span.
//  - Per-instruction coalescing unchanged: lanes dense, 1 KB/wave-instr.
//  - Row i = ((blk*2048 + u*256 + tid)>>3)&31 = tid>>3: CONSTANT per thread
//    across all 8 accesses (2048 and 256 are multiples of 8*32). So the
//    zero-row predicate + column mask class are computed ONCE, the branch
//    executes once, and all 8 loads issue back-to-back -> 8 outstanding
//    loads per wave (was 1) and 8x fewer workgroups (4096 vs 32768).
//  - Zero rows (i%3==0, 11/32): store zeros, never load (rows are 128B
//    aligned segments -> skipped rows cost no HBM fetch).
// Non-temporal: poison fill evicts caches between iterations; no reuse.

typedef float vf4 __attribute__((ext_vector_type(4)));

constexpr int N_TOTAL = 64 * 512 * 32 * 32;   // 33,554,432 floats
constexpr int N_F4    = N_TOTAL / 4;          // 8,388,608 float4s
constexpr int FPT     = 8;                    // float4s per thread
constexpr int BLK     = 256;
constexpr int NBLK    = N_F4 / (BLK * FPT);   // 4096 blocks

__global__ __launch_bounds__(256) void unfoldfold_mask_kernel(
    const vf4* __restrict__ x, vf4* __restrict__ out) {
    int tid  = threadIdx.x;
    int base = blockIdx.x * (BLK * FPT) + tid;   // f4 index at u=0
    int i    = tid >> 3;                         // row within 32x32 image (0..31)
    if ((i % 3) == 0) {
        vf4 z = (vf4)(0.f);
        #pragma unroll
        for (int u = 0; u < FPT; ++u)
            __builtin_nontemporal_store(z, &out[base + u * BLK]);
        return;
    }
    vf4 v[FPT];
    #pragma unroll
    for (int u = 0; u < FPT; ++u)
        v[u] = __builtin_nontemporal_load(&x[base + u * BLK]);
    // j0 = (tid&7)*4; element e zeroed iff (j0+e)%3==0; m = j0%3 = (tid&7)%3
    int m = (tid & 7) % 3;
    #pragma unroll
    for (int u = 0; u < FPT; ++u) {
        if (m == 0)      { v[u].x = 0.f; v[u].w = 0.f; }   // e=0,3
        else if (m == 1) { v[u].z = 0.f; }                 // e=2
        else             { v[u].y = 0.f; }                 // e=1
        __builtin_nontemporal_store(v[u], &out[base + u * BLK]);
    }
}

extern "C" void kernel_launch(void* const* d_in, const int* in_sizes, int n_in,
                              void* d_out, int out_size, void* d_ws, size_t ws_size,
                              hipStream_t stream) {
    const vf4* x = (const vf4*)d_in[0];
    vf4* out = (vf4*)d_out;
    unfoldfold_mask_kernel<<<NBLK, BLK, 0, stream>>>(x, out);
}